// Round 1
// baseline (168.572 us; speedup 1.0000x reference)
//
#include <hip/hip_runtime.h>
#include <math.h>

// Parallel NeRF: each atom placement k is a rigid transform A_k = A_{k-1} * Dk
// where Dk depends only on (bond_angle, bond_length, torsion) of atom k.
// Positions = translation part of the prefix products. We do a per-chain
// block scan: 256 threads x 6 atoms/thread over the 1533 placements.

struct Xform { float r[9]; float t[3]; };  // r row-major 3x3, t translation

__device__ __forceinline__ void xf_identity(Xform& A) {
  A.r[0]=1.f; A.r[1]=0.f; A.r[2]=0.f;
  A.r[3]=0.f; A.r[4]=1.f; A.r[5]=0.f;
  A.r[6]=0.f; A.r[7]=0.f; A.r[8]=1.f;
  A.t[0]=0.f; A.t[1]=0.f; A.t[2]=0.f;
}

// C = A o B  (A applied after B; A is the EARLIER prefix: (A*B)(p)=A(B(p)))
__device__ __forceinline__ Xform xf_compose(const Xform& A, const Xform& B) {
  Xform C;
#pragma unroll
  for (int i = 0; i < 3; ++i) {
    float a0 = A.r[3*i+0], a1 = A.r[3*i+1], a2 = A.r[3*i+2];
    C.r[3*i+0] = a0*B.r[0] + a1*B.r[3] + a2*B.r[6];
    C.r[3*i+1] = a0*B.r[1] + a1*B.r[4] + a2*B.r[7];
    C.r[3*i+2] = a0*B.r[2] + a1*B.r[5] + a2*B.r[8];
    C.t[i]     = a0*B.t[0] + a1*B.t[1] + a2*B.t[2] + A.t[i];
  }
  return C;
}

// Closed-form local step transform.
// d_local = (-L cos(th), L cos(ta) sin(th), L sin(ta) sin(th))
// R columns: [u, (-s_th, -c_th c_ta, -c_th s_ta), (0, -s_ta, c_ta)], u=d_local/L
__device__ __forceinline__ Xform xf_delta(float theta, float len, float tau) {
  float st, ct, sx, cx;
  __sincosf(theta, &st, &ct);
  __sincosf(tau, &sx, &cx);
  float ux = -ct, uy = cx*st, uz = sx*st;
  Xform D;
  D.r[0] = ux;     D.r[1] = -st;    D.r[2] = 0.f;
  D.r[3] = uy;     D.r[4] = -ct*cx; D.r[5] = -sx;
  D.r[6] = uz;     D.r[7] = -ct*sx; D.r[8] = cx;
  D.t[0] = len*ux; D.t[1] = len*uy; D.t[2] = len*uz;
  return D;
}

__device__ __forceinline__ void xf_store(float* p, const Xform& A) {
#pragma unroll
  for (int i = 0; i < 9; ++i) p[i] = A.r[i];
#pragma unroll
  for (int i = 0; i < 3; ++i) p[9+i] = A.t[i];
}
__device__ __forceinline__ void xf_load(const float* p, Xform& A) {
#pragma unroll
  for (int i = 0; i < 9; ++i) A.r[i] = p[i];
#pragma unroll
  for (int i = 0; i < 3; ++i) A.t[i] = p[9+i];
}

#define LCH 512
#define NRES 511          // residues placed per chain
#define SCAN_STRIDE 13    // 12 floats + 1 pad -> conflict-free (13 coprime 32)

static __device__ const float c_init[9] = {
  17.047f, 14.099f, 3.625f,    // N_INIT
  16.967f, 12.784f, 4.338f,    // CA_INIT
  15.685f, 12.755f, 5.133f };  // C_INIT

__global__ __launch_bounds__(256) void nerf_scan_kernel(
    const float* __restrict__ g_phi, const float* __restrict__ g_psi,
    const float* __restrict__ g_omg, const float* __restrict__ g_bl,
    const float* __restrict__ g_ba, float* __restrict__ g_out)
{
  __shared__ float s_psi[NRES];
  __shared__ float s_omg[NRES];
  __shared__ float s_phi[NRES];     // s_phi[j] = phi[j+1]
  __shared__ float s_bl[3*NRES];
  __shared__ float s_ba[3*NRES];
  __shared__ float s_scan[256*SCAN_STRIDE];

  const int b = blockIdx.x;
  const int t = threadIdx.x;

  const float* phir = g_phi + (size_t)b*LCH;
  const float* psir = g_psi + (size_t)b*LCH;
  const float* omgr = g_omg + (size_t)b*LCH;
  const float* blr  = g_bl  + (size_t)b*LCH*3;
  const float* bar  = g_ba  + (size_t)b*LCH*3;

  for (int i = t; i < NRES; i += 256) {
    s_psi[i] = psir[i];
    s_omg[i] = omgr[i];
    s_phi[i] = phir[i+1];
  }
  for (int i = t; i < 3*NRES; i += 256) {
    s_bl[i] = blr[i];
    s_ba[i] = bar[i];
  }
  __syncthreads();

  // ---- Phase A: per-thread serial product of 6 deltas (2 residues) ----
  Xform P; xf_identity(P);
#pragma unroll
  for (int e = 0; e < 2; ++e) {
    int j = 2*t + e;
    if (j < NRES) {
      // N:  theta=ba[j][1], L=bl[j][2], tau=psi[j]
      P = xf_compose(P, xf_delta(s_ba[3*j+1], s_bl[3*j+2], s_psi[j]));
      // CA: theta=ba[j][2], L=bl[j][0], tau=omega[j]
      P = xf_compose(P, xf_delta(s_ba[3*j+2], s_bl[3*j+0], s_omg[j]));
      // C:  theta=ba[j][0], L=bl[j][1], tau=phi[j+1]
      P = xf_compose(P, xf_delta(s_ba[3*j+0], s_bl[3*j+1], s_phi[j]));
    }
  }
  xf_store(&s_scan[t*SCAN_STRIDE], P);
  __syncthreads();

  // ---- Phase B: Hillis-Steele inclusive scan (non-commutative) ----
  for (int d = 1; d < 256; d <<= 1) {
    Xform left;
    bool act = (t >= d);
    if (act) xf_load(&s_scan[(t-d)*SCAN_STRIDE], left);
    __syncthreads();
    if (act) {
      P = xf_compose(left, P);
      xf_store(&s_scan[t*SCAN_STRIDE], P);
    }
    __syncthreads();
  }

  // ---- base = A_init * exclusive_prefix(t) ----
  Xform A;
  {
    // Initial frame from (N_INIT, CA_INIT, C_INIT) — constant-folds.
    const float ax=17.047f, ay=14.099f, az=3.625f;
    const float bx_=16.967f, by_=12.784f, bz_=4.338f;
    const float cx_=15.685f, cy_=12.755f, cz_=5.133f;
    float abx=bx_-ax, aby=by_-ay, abz=bz_-az;
    float vx=cx_-bx_, vy=cy_-by_, vz=cz_-bz_;
    float vn = sqrtf(vx*vx+vy*vy+vz*vz) + 1e-8f;
    vx/=vn; vy/=vn; vz/=vn;
    float crx = aby*vz - abz*vy;
    float cry = abz*vx - abx*vz;
    float crz = abx*vy - aby*vx;
    float cn = sqrtf(crx*crx+cry*cry+crz*crz) + 1e-8f;
    float nx=crx/cn, ny=cry/cn, nz=crz/cn;
    float mx = ny*vz - nz*vy;
    float my = nz*vx - nx*vz;
    float mz = nx*vy - ny*vx;
    Xform I0;
    I0.r[0]=vx; I0.r[1]=mx; I0.r[2]=nx;
    I0.r[3]=vy; I0.r[4]=my; I0.r[5]=ny;
    I0.r[6]=vz; I0.r[7]=mz; I0.r[8]=nz;
    I0.t[0]=cx_; I0.t[1]=cy_; I0.t[2]=cz_;
    if (t == 0) {
      A = I0;
    } else {
      Xform E; xf_load(&s_scan[(t-1)*SCAN_STRIDE], E);
      A = xf_compose(I0, E);
    }
  }

  float* orow = g_out + (size_t)b * (3*LCH) * 3;
  if (t < 9) orow[t] = c_init[t];  // init triple verbatim

  // ---- Phase C: replay deltas with global prefix, write positions ----
#pragma unroll
  for (int e = 0; e < 2; ++e) {
    int j = 2*t + e;
    if (j < NRES) {
      float* o = orow + (size_t)(3 + 3*j) * 3;
      A = xf_compose(A, xf_delta(s_ba[3*j+1], s_bl[3*j+2], s_psi[j]));
      o[0]=A.t[0]; o[1]=A.t[1]; o[2]=A.t[2];
      A = xf_compose(A, xf_delta(s_ba[3*j+2], s_bl[3*j+0], s_omg[j]));
      o[3]=A.t[0]; o[4]=A.t[1]; o[5]=A.t[2];
      A = xf_compose(A, xf_delta(s_ba[3*j+0], s_bl[3*j+1], s_phi[j]));
      o[6]=A.t[0]; o[7]=A.t[1]; o[8]=A.t[2];
    }
  }
}

extern "C" void kernel_launch(void* const* d_in, const int* in_sizes, int n_in,
                              void* d_out, int out_size, void* d_ws, size_t ws_size,
                              hipStream_t stream) {
  const float* phi = (const float*)d_in[0];
  const float* psi = (const float*)d_in[1];
  const float* omg = (const float*)d_in[2];
  const float* bl  = (const float*)d_in[3];
  const float* ba  = (const float*)d_in[4];
  float* out = (float*)d_out;
  const int B = in_sizes[0] / LCH;  // 4096
  hipLaunchKernelGGL(nerf_scan_kernel, dim3(B), dim3(256), 0, stream,
                     phi, psi, omg, bl, ba, out);
}